// Round 13
// baseline (495.682 us; speedup 1.0000x reference)
//
#include <hip/hip_runtime.h>
#include <math.h>

#define N_TOK 8192
#define DIM   1024
#define HID   2048
#define NE    8
#define NPAIR (N_TOK * 2)          // 16384 (token, expert) pairs exactly
#define CAPP  (NPAIR + NE * 128)   // 17408: expert regions padded to 128 rows
#define TAIL  (N_TOK * DIM)        // offset of scalar outputs in d_out

typedef __bf16 bf16x8_t __attribute__((ext_vector_type(8)));
typedef float  f32x4_t  __attribute__((ext_vector_type(4)));

__device__ __forceinline__ unsigned short f2bf(float f) {
  union { float f; unsigned u; } v; v.f = f;
  unsigned r = v.u + 0x7fffu + ((v.u >> 16) & 1u);   // RNE
  return (unsigned short)(r >> 16);
}

__device__ __forceinline__ float bf2f(unsigned short h) {
  union { unsigned u; float f; } v; v.u = ((unsigned)h) << 16;
  return v.f;
}

// erff kept in gemm1 (measured ladder: direct+erff=112us < staged+fast=124
// < direct+fast=152). The libm erff's VALU pacing lets direct u16 stores
// drain under the next tile's K-loop without RMW bursts.
__device__ __forceinline__ float gelu_exact(float v) {
  return 0.5f * v * (1.f + erff(v * 0.70710678118654752440f));
}

// async global->LDS DMA, 16B/lane; LDS base wave-uniform, HW scatters lane*16.
__device__ __forceinline__ void load16_lds(const void* g, void* l) {
  __builtin_amdgcn_global_load_lds(
      (const __attribute__((address_space(1))) unsigned int*)g,
      (__attribute__((address_space(3))) unsigned int*)l, 16, 0, 0);
}

// =======================================================================
// Fragment-chunk global layout (R4): a matrix [R rows][Kd k] is stored as
// 1KB chunks; chunk c = (r>>4)*(Kd/32) + (k>>5); within a chunk, lane
// l = (k>>3&3)*16 + (r&15) owns 16B = 8 shorts (k&7 fastest).
//
// GEMMs: persistent 1024 blocks (4/CU hard cap: 128 regs/wave, 512-reg
// SIMD file, m69), R4 inner loop (128x128 tile, 4 waves, BK=64, 32KB
// LDS); gemm1 = direct-store+erff (measured fastest).
//
// R17: (a) balanced CONTIGUOUS tile ranges [swz*nt/1024,(swz+1)*nt/1024)
// replace the stride loop: with stride, all 3rd-round gemm1 tiles
// belonged to bid%8==0 blocks -> ALL on XCD 0 (round-robin dispatch);
// the whole tail round ran on 32 CUs (measured occupancy 31% vs 50%
// static). Ranges spread the +1-tile blocks across all XCDs; L2
// locality preserved (consecutive tiles share A-panels). Isolates the
// range change from R10 (whose regression was VGPR spill, not ranges).
// (b) router fused into the prep kernel as blocks [4096,4608), race-
// free: per-block PARTIAL stats (plain stores, no zeroing needed);
// scatter reduces partials in-block; cursor zeroed by router block 0
// (consumed only by later-stream scatter). Memset gone: 6 enqueues.
// =======================================================================

#define W2F_BLOCKS 4096
#define R_BLOCKS   512
#define R_TPW      (N_TOK / (R_BLOCKS * 4))   // 4 tokens per wave

// ---------------- weights fp32 [z][Kd][R] -> frag-chunk bf16 (coalesced) ----------------
template<int KD, int RR>
__device__ __forceinline__ void w2f_body(const float* __restrict__ src,
                                         unsigned short* __restrict__ dst,
                                         int bx, int kblk, int z,
                                         unsigned short (*L)[34], int t) {
  constexpr int KD32 = KD / 32;
  int r0 = bx << 8;
  const float* s = src + (size_t)z * KD * RR + (size_t)(kblk * 32) * RR + r0 + t;
  #pragma unroll
  for (int kk = 0; kk < 32; ++kk)
    L[t][kk] = f2bf(s[(size_t)kk * RR]);   // 256 consecutive floats per kk: 1KB coalesced
  __syncthreads();
  int lane = t & 63, m16 = lane & 15, q = lane >> 4;
  unsigned short* d = dst + (size_t)z * KD * RR;
  #pragma unroll
  for (int p = 0; p < 4; ++p) {
    int ci = p * 4 + (t >> 6);            // chunk-in-block 0..15
    int c = ((r0 >> 4) + ci) * KD32 + kblk;
    uint4 v = *(const uint4*)&L[ci * 16 + m16][q * 8];   // 8 shorts k = q*8..q*8+7
    *(uint4*)(d + (size_t)c * 512 + lane * 8) = v;
  }
}

// prep: blocks [0,4096) convert weights; blocks [4096,4608) run the router,
// writing PER-BLOCK partial stats (no cross-block races; no zero-init needed).
// Router block 0 zeroes cursor (consumed only by the later scatter kernel).
__global__ __launch_bounds__(256) void prep_kernel(
    const float* __restrict__ W1, const float* __restrict__ W2,
    unsigned short* __restrict__ W1f, unsigned short* __restrict__ W2f,
    const float* __restrict__ x, const float* __restrict__ gW, const float* __restrict__ gb,
    int* __restrict__ tok_e, float* __restrict__ tok_g,
    int* __restrict__ pcnt,      // [R_BLOCKS][NE]
    float* __restrict__ pimp,    // [R_BLOCKS][NE]
    float* __restrict__ pent,    // [R_BLOCKS]
    int* __restrict__ cursor) {  // [NE]
  __shared__ unsigned short L[256][34];   // w2f path
  __shared__ int s_cnt[NE];               // router path
  __shared__ float s_imp[NE];
  __shared__ float s_ent;
  int t = threadIdx.x;
  int f = blockIdx.x;
  if (f < 2048) {
    int z = f >> 8, r = f & 255;
    w2f_body<DIM, HID>(W1, W1f, r & 7, r >> 3, z, L, t);
    return;
  }
  if (f < W2F_BLOCKS) {
    int f2 = f - 2048;
    int z = f2 >> 8, r = f2 & 255;
    w2f_body<HID, DIM>(W2, W2f, r & 3, r >> 2, z, L, t);
    return;
  }
  // ---------------- router path ----------------
  int rb = f - W2F_BLOCKS;                // 0..511
  if (rb == 0 && t < NE) cursor[t] = 0;   // safe: scatter runs in a later kernel
  if (t < NE) { s_cnt[t] = 0; s_imp[t] = 0.f; }
  if (t == 0) s_ent = 0.f;
  __syncthreads();
  int wid = t >> 6, lane = t & 63;
  int t0 = (rb * 4 + wid) * R_TPW;
  float imp_loc[8] = {0.f, 0.f, 0.f, 0.f, 0.f, 0.f, 0.f, 0.f};
  float ent_loc = 0.f;
  for (int tt = 0; tt < R_TPW; ++tt) {
    int n = t0 + tt;
    const float* xr = x + (size_t)n * DIM;
    float p[8] = {0.f, 0.f, 0.f, 0.f, 0.f, 0.f, 0.f, 0.f};
    #pragma unroll
    for (int it = 0; it < DIM / 64; ++it) {
      int d = lane + (it << 6);
      float xv = xr[d];
      const float4* g4 = (const float4*)(gW + (size_t)d * NE);
      float4 a = g4[0], b = g4[1];
      p[0] += xv * a.x; p[1] += xv * a.y; p[2] += xv * a.z; p[3] += xv * a.w;
      p[4] += xv * b.x; p[5] += xv * b.y; p[6] += xv * b.z; p[7] += xv * b.w;
    }
    #pragma unroll
    for (int e = 0; e < 8; ++e)
      for (int o = 32; o > 0; o >>= 1) p[e] += __shfl_down(p[e], o, 64);
    if (lane == 0) {
      float lg[8];
      #pragma unroll
      for (int e = 0; e < 8; ++e) lg[e] = p[e] + gb[e];
      int i0 = 0;
      #pragma unroll
      for (int e = 1; e < 8; ++e) if (lg[e] > lg[i0]) i0 = e;   // ties -> lowest idx
      int i1 = (i0 == 0) ? 1 : 0;
      #pragma unroll
      for (int e = 0; e < 8; ++e) if (e != i0 && lg[e] > lg[i1]) i1 = e;
      float d1 = expf(lg[i1] - lg[i0]);
      float g0 = 1.f / (1.f + d1);
      float g1 = d1 * g0;
      tok_e[2 * n] = i0; tok_e[2 * n + 1] = i1;
      tok_g[2 * n] = g0; tok_g[2 * n + 1] = g1;
      atomicAdd(&s_cnt[i0], 1);
      atomicAdd(&s_cnt[i1], 1);
      float mx = lg[i0], s = 0.f, pe[8];
      #pragma unroll
      for (int e = 0; e < 8; ++e) { pe[e] = expf(lg[e] - mx); s += pe[e]; }
      float inv = 1.f / s;
      #pragma unroll
      for (int e = 0; e < 8; ++e) {
        float pr = pe[e] * inv;
        imp_loc[e] += pr;
        ent_loc -= pr * logf(pr + 1e-8f);
      }
    }
  }
  if (lane == 0) {
    #pragma unroll
    for (int e = 0; e < 8; ++e) atomicAdd(&s_imp[e], imp_loc[e]);
    atomicAdd(&s_ent, ent_loc);
  }
  __syncthreads();
  if (t < NE) { pcnt[rb * NE + t] = s_cnt[t]; pimp[rb * NE + t] = s_imp[t]; }
  if (t == NE) pent[rb] = s_ent;
}

// ---------------- scatter: reduce partials, bucket pairs, publish stats ----------------
__global__ __launch_bounds__(256) void scatter_kernel(
    const int* __restrict__ tok_e, const float* __restrict__ tok_g,
    const int* __restrict__ pcnt, const float* __restrict__ pimp,
    const float* __restrict__ pent,
    int* __restrict__ cursor, int* __restrict__ poffs_g, int* __restrict__ cnt_out,
    float* __restrict__ out_tail,
    int* __restrict__ row_token, float* __restrict__ row_gate,
    int* __restrict__ pair_slot) {
  __shared__ int s_cnt[NE], s_base[NE], s_rank[NE];
  __shared__ int g_cnt[NE];
  __shared__ float g_imp[NE], g_ent;
  int tid = threadIdx.x;
  if (tid < NE) { s_cnt[tid] = 0; s_rank[tid] = 0; g_cnt[tid] = 0; g_imp[tid] = 0.f; }
  if (tid == 0) g_ent = 0.f;
  __syncthreads();
  // reduce pcnt[512][8]: thread t -> expert e=t&7, row-group rg=t>>3 (32 groups x 16 rows)
  {
    int e = tid & 7, rg = tid >> 3;
    int acc = 0;
    #pragma unroll
    for (int r = 0; r < 16; ++r) acc += pcnt[(rg * 16 + r) * NE + e];
    atomicAdd(&g_cnt[e], acc);
  }
  if (blockIdx.x == 0) {                  // block 0 also reduces imp/ent
    int e = tid & 7, rg = tid >> 3;
    float fa = 0.f;
    #pragma unroll
    for (int r = 0; r < 16; ++r) fa += pimp[(rg * 16 + r) * NE + e];
    atomicAdd(&g_imp[e], fa);
    float ea = pent[tid] + pent[tid + 256];
    atomicAdd(&g_ent, ea);
  }
  int n = blockIdx.x * 256 + tid;
  int e0 = tok_e[2 * n], e1 = tok_e[2 * n + 1];
  atomicAdd(&s_cnt[e0], 1);
  atomicAdd(&s_cnt[e1], 1);
  __syncthreads();
  if (tid < NE) {
    int po = 0;
    for (int e = 0; e < tid; ++e) po += ((g_cnt[e] + 127) >> 7) << 7;   // padded prefix
    s_base[tid] = po + atomicAdd(&cursor[tid], s_cnt[tid]);
  }
  __syncthreads();
  int r0 = atomicAdd(&s_rank[e0], 1);
  int s0 = s_base[e0] + r0;
  row_token[s0] = n; row_gate[s0] = tok_g[2 * n]; pair_slot[2 * n] = s0;
  int r1 = atomicAdd(&s_rank[e1], 1);
  int s1 = s_base[e1] + r1;
  row_token[s1] = n; row_gate[s1] = tok_g[2 * n + 1]; pair_slot[2 * n + 1] = s1;
  if (blockIdx.x == 0 && tid == 0) {
    const float invN = 1.f / (float)N_TOK;
    int off = 0; float bal = 0.f, util = 0.f;
    for (int e = 0; e < NE; ++e) {
      poffs_g[e] = off;
      cnt_out[e] = g_cnt[e];
      off += ((g_cnt[e] + 127) >> 7) << 7;
      float ld = (float)g_cnt[e] * invN;
      float im = g_imp[e] * invN;
      out_tail[3 + e] = ld;        // load
      out_tail[11 + e] = im;       // importance
      bal += im * ld;
      util -= ld * logf(ld + 1e-8f);
    }
    poffs_g[NE] = off;
    out_tail[0] = (float)NE * bal; // balance_loss
    out_tail[1] = g_ent * invN;    // entropy
    out_tail[2] = util;            // utilization_entropy
  }
}

// ---------------- gather bucketed A (x rows -> frag-chunk bf16, Kd=1024) ----------------
#define GA_BLOCKS ((CAPP >> 4) * 32 / 4)   // 8704 worst-case (4 chunks/block)
__global__ __launch_bounds__(256) void gather_a1(
    const float* __restrict__ x, const int* __restrict__ row_token,
    const int* __restrict__ cnt, const int* __restrict__ poffs,
    unsigned short* __restrict__ Ab1) {
  int po[NE + 1];
  #pragma unroll
  for (int i = 0; i <= NE; ++i) po[i] = poffs[i];
  int nch = (po[NE] >> 4) * 32;            // actual total chunks
  int cl = blockIdx.x * 4 + (threadIdx.x >> 6);
  if (cl >= nch) return;                   // wave-uniform exit
  int lane = threadIdx.x & 63, m16 = lane & 15, q = lane >> 4;
  int sb = cl >> 5, kblk = cl & 31;
  int slot = (sb << 4) + m16;
  int e = 0;
  #pragma unroll
  for (int k = 1; k < NE; ++k) e += (po[k] <= slot) ? 1 : 0;   // monotone scan
  int sl = slot - po[e];
  int tok = (sl < cnt[e]) ? row_token[slot] : 0;   // pad rows: token 0 (finite)
  int k = kblk * 32 + q * 8;
  const float4* sp = (const float4*)(x + (size_t)tok * DIM + k);
  float4 v0 = sp[0], v1 = sp[1];
  unsigned short t[8] = {f2bf(v0.x), f2bf(v0.y), f2bf(v0.z), f2bf(v0.w),
                         f2bf(v1.x), f2bf(v1.y), f2bf(v1.z), f2bf(v1.w)};
  *(uint4*)(Ab1 + ((size_t)sb * 32 + kblk) * 512 + lane * 8) = *(uint4*)t;
}

#define GEMM_BLOCKS 1024   // 4 blocks/CU x 256 CU (hard cap: 128 regs/wave, m69)

// XCD-bijective swizzle (T1): 1024 % 8 == 0 so the simple form is bijective.
__device__ __forceinline__ int xcd_swz(int bid) {
  return (bid & 7) * (GEMM_BLOCKS >> 3) + (bid >> 3);
}

// ---------------- GEMM1: He = gelu(Ab1 @ W1f + b1), He in frag order (Kd=2048) ----------------
// Persistent; balanced contiguous ranges (R17); direct u16 stores + erff.
__global__ __launch_bounds__(256, 4) void expert_gemm1(
    const unsigned short* __restrict__ Ab1,   // frag, Kd32=32
    const unsigned short* __restrict__ W1f,   // [E] frag, rows=HID, Kd32=32
    const float* __restrict__ b1,             // [E][H]
    const int* __restrict__ poffs,
    unsigned short* __restrict__ He) {        // frag, rows=CAPP, Kd32=64
  __shared__ __align__(16) unsigned short As[8192], Bs[8192];
  __shared__ int s_po[NE + 1];
  int tid = threadIdx.x, wid = tid >> 6, lane = tid & 63;
  if (tid <= NE) s_po[tid] = poffs[tid];
  __syncthreads();
  int nt = (s_po[NE] >> 7) << 4;              // row-tiles(128) x 16 col-tiles
  int m16 = lane & 15, q = lane >> 4;
  int wr = (wid & 1) << 6, wc = (wid >> 1) << 6;
  int ra = wr >> 4, rc = wc >> 4;
  unsigned short* lA = As + wid * 4 * 512;
  unsigned short* lB = Bs + wid * 4 * 512;
  f32x4_t zero4 = {0.f, 0.f, 0.f, 0.f};
  int swz = xcd_swz(blockIdx.x);
  int lo = (int)(((long long)swz * nt) >> 10);
  int hi = (int)(((long long)(swz + 1) * nt) >> 10);

  for (int tile = lo; tile < hi; ++tile) {
    int rt = tile >> 4, ct = tile & 15;
    int col0 = ct << 7;
    int row0 = rt << 7;                       // absolute slot row (region-aligned)
    int e = 0;
    while (e + 1 < NE && s_po[e + 1] <= row0) ++e;
    const unsigned short* Ag = Ab1 + ((size_t)((rt << 3) + wid * 2) * 32) * 512 + lane * 8;
    const unsigned short* Bg = W1f + (size_t)e * HID * DIM
                             + ((size_t)((col0 >> 4) + wid * 2) * 32) * 512 + lane * 8;
    f32x4_t acc[4][4];
    #pragma unroll
    for (int i = 0; i < 4; ++i)
      #pragma unroll
      for (int j = 0; j < 4; ++j) acc[i][j] = zero4;

    for (int k0 = 0; k0 < DIM; k0 += 64) {
      int kc = (k0 >> 5) * 512;
      load16_lds(Ag + kc,                  lA);
      load16_lds(Ag + kc + 512,            lA + 512);
      load16_lds(Ag + kc + 32 * 512,       lA + 1024);
      load16_lds(Ag + kc + 32 * 512 + 512, lA + 1536);
      load16_lds(Bg + kc,                  lB);
      load16_lds(Bg + kc + 512,            lB + 512);
      load16_lds(Bg + kc + 32 * 512,       lB + 1024);
      load16_lds(Bg + kc + 32 * 512 + 512, lB + 1536);
      __syncthreads();
      #pragma unroll
      for (int ks = 0; ks < 2; ++ks) {
        bf16x8_t a[4], b[4];
        #pragma unroll
        for (int i = 0; i < 4; ++i) {
          a[i] = *(const bf16x8_t*)&As[((ra + i) * 2 + ks) * 512 + lane * 8];
          b[i] = *(const bf16x8_t*)&Bs[((rc + i) * 2 + ks) * 512 + lane * 8];
        }
        #pragma unroll
        for (int i = 0; i < 4; ++i)
          #pragma unroll
          for (int j = 0; j < 4; ++j)
            acc[i][j] = __builtin_amdgcn_mfma_f32_16x16x32_bf16(a[i], b[j], acc[i][j], 0, 0, 0);
      }
      __syncthreads();
    }

    const float* b1e = b1 + (size_t)e * HID;
    int sb = rt << 3;
    #pragma unroll
    for (int i = 0; i < 4; ++i) {
      size_t sblk = (size_t)(sb + ra + i);
      #pragma unroll
      for (int rr = 0; rr < 4; ++rr) {
        int s15 = q * 4 + rr;   // slot & 15
        #pragma unroll
        for (int j = 0; j < 4; ++j) {
          int col = col0 + wc + j * 16 + m16;
          float v = acc[i][j][rr] + b1e[col];
          size_t off = (sblk * 64 + (col >> 5)) * 512 + (((col >> 3) & 3) * 16 + s15) * 8 + (col & 7);
          He[off] = f2bf(gelu_exact(v));
        }
      }
    }
  }
}

// ---------------- GEMM2: yb[slot] = He @ W2f (row-major out; bias+gate in LN) ----------------
__global__ __launch_bounds__(256, 4) void expert_gemm2(
    const unsigned short* __restrict__ He,    // frag, Kd32=64
    const unsigned short* __restrict__ W2f,   // [E] frag, rows=DIM, Kd32=64
    const int* __restrict__ poffs,
    unsigned short* __restrict__ yb) {        // [CAPP][DIM] row-major
  __shared__ __align__(16) unsigned short As[8192], Bs[8192];
  __shared__ int s_po[NE + 1];
  int tid = threadIdx.x, wid = tid >> 6, lane = tid & 63;
  if (tid <= NE) s_po[tid] = poffs[tid];
  __syncthreads();
  int nt = (s_po[NE] >> 7) << 3;              // row-tiles(128) x 8 col-tiles
  int m16 = lane & 15, q = lane >> 4;
  int wr = (wid & 1) << 6, wc = (wid >> 1) << 6;
  int ra = wr >> 4, rc = wc >> 4;
  unsigned short* lA = As + wid * 4 * 512;
  unsigned short* lB = Bs + wid * 4 * 512;
  f32x4_t zero4 = {0.f, 0.f, 0.f, 0.f};
  int swz = xcd_swz(blockIdx.x);
  int lo = (int)(((long long)swz * nt) >> 10);
  int hi = (int)(((long long)(swz + 1) * nt) >> 10);

  for (int tile = lo; tile < hi; ++tile) {
    int rt = tile >> 3, ct = tile & 7;
    int row0 = rt << 7;
    int col0 = ct << 7;
    int e = 0;
    while (e + 1 < NE && s_po[e + 1] <= row0) ++e;
    const unsigned short* Ag = He + ((size_t)((rt << 3) + wid * 2) * 64) * 512 + lane * 8;
    const unsigned short* Bg = W2f + (size_t)e * DIM * HID
                             + ((size_t)((col0 >> 4) + wid * 2) * 64) * 512 + lane * 8;
    f32x4_t acc[4][4];
    #pragma unroll
    for (int i = 0; i < 4; ++i)
      #pragma unroll
      for (int j = 0; j < 4; ++j) acc[i][j] = zero4;

    for (int k0 = 0; k0 < HID; k0 += 64) {
      int kc = (k0 >> 5) * 512;
      load16_lds(Ag + kc,                  lA);
      load16_lds(Ag + kc + 512,            lA + 512);
      load16_lds(Ag + kc + 64 * 512,       lA + 1024);
      load16_lds(Ag + kc + 64 * 512 + 512, lA + 1536);
      load16_lds(Bg + kc,                  lB);
      load16_lds(Bg + kc + 512,            lB + 512);
      load16_lds(Bg + kc + 64 * 512,       lB + 1024);
      load16_lds(Bg + kc + 64 * 512 + 512, lB + 1536);
      __syncthreads();
      #pragma unroll
      for (int ks = 0; ks < 2; ++ks) {
        bf16x8_t a[4], b[4];
        #pragma unroll
        for (int i = 0; i < 4; ++i) {
          a[i] = *(const bf16x8_t*)&As[((ra + i) * 2 + ks) * 512 + lane * 8];
          b[i] = *(const bf16x8_t*)&Bs[((rc + i) * 2 + ks) * 512 + lane * 8];
        }
        #pragma unroll
        for (int i = 0; i < 4; ++i)
          #pragma unroll
          for (int j = 0; j < 4; ++j)
            acc[i][j] = __builtin_amdgcn_mfma_f32_16x16x32_bf16(a[i], b[j], acc[i][j], 0, 0, 0);
      }
      __syncthreads();
    }

    #pragma unroll
    for (int i = 0; i < 4; ++i) {
      #pragma unroll
      for (int rr = 0; rr < 4; ++rr) {
        size_t slot = (size_t)(row0 + wr + i * 16 + q * 4 + rr);
        #pragma unroll
        for (int j = 0; j < 4; ++j) {
          int col = col0 + wc + j * 16 + m16;
          yb[slot * DIM + col] = f2bf(acc[i][j][rr]);
        }
      }
    }
  }
}

// ---------------- gather + gate + bias + residual + LayerNorm (vectorized) ----------------
__global__ __launch_bounds__(256) void ln_kernel(
    const float* __restrict__ x, const unsigned short* __restrict__ yb,
    const int* __restrict__ tok_e, const float* __restrict__ tok_g,
    const int* __restrict__ pair_slot, const float* __restrict__ b2,
    const float* __restrict__ gamma, const float* __restrict__ beta,
    float* __restrict__ out) {
  int n = blockIdx.x, tid = threadIdx.x;
  int e0 = tok_e[2 * n], e1 = tok_e[2 * n + 1];
  float g0 = tok_g[2 * n], g1 = tok_g[2 * n + 1];
  size_t s0 = (size_t)pair_slot[2 * n], s1 = (size_t)pair_slot[2 * n + 1];
  const float* xr = x + (size_t)n * DIM;
  const unsigned short* y0 = yb + s0 * DIM;
  const unsigned short* y1 = yb + s1 * DIM;
  const float* b2e0 = b2 + (size_t)e0 * DIM;
  const float* b2e1 = b2 + (size_t)e1 * DIM;
  int d0 = tid << 2;   // thread owns elements d0..d0+3 (256*4 = 1024)
  float4 xv  = *(const float4*)(xr + d0);
  ushort4 yv0 = *(const ushort4*)(y0 + d0);
  ushort4 yv1 = *(const ushort4*)(y1 + d0);
  float4 bv0 = *(const float4*)(b2e0 + d0);
  float4 bv1 = *(const float4*)(b2e1 + d0);
  float z[4], s = 0.f, s2 = 0.f;
  {
    const float* xp = (const float*)&xv;
    const unsigned short* y0p = (const unsigned short*)&yv0;
    const unsigned short* y1p = (const unsigned short*)&yv1;
    const float* b0p = (const float*)&bv0;
    const float* b1p = (const float*)&bv1;
    #pragma unroll
    for (int jj = 0; jj < 4; ++jj) {
      float v = xp[jj] + g0 * (bf2f(y0p[jj]) + b0p[jj]) + g1 * (bf2f(y1p[jj]) + b1p[jj]);
      z[jj] = v; s += v; s2 += v * v;
    }
  }
  for (int o = 32; o > 0; o >>= 1) { s += __shfl_down(s, o, 64); s2 += __shfl_down(s2, o, 64); }
  __shared__ float rs[4], rs2[4];
  int wid = tid >> 6, lane = tid & 63;
  if (lane == 0) { rs[wid] = s; rs2[wid] = s2; }
  __syncthreads();
  float ts = rs[0] + rs[1] + rs[2] + rs[3];
  float ts2 = rs2[0] + rs2[1] + rs2[2] + rs2[3];
  float mu = ts * (1.f / DIM);
  float var = ts2 * (1.f / DIM) - mu * mu;
  float rstd = rsqrtf(var + 1e-5f);
  float4 gv = *(const float4*)(gamma + d0);
  float4 bv = *(const float4*)(beta + d0);
  float4 ov;
  {
    const float* gp = (const float*)&gv;
    const float* bp = (const float*)&bv;
    float* op = (float*)&ov;
    #pragma unroll
    for (int jj = 0; jj < 4; ++jj)
      op[jj] = (z[jj] - mu) * rstd * gp[jj] + bp[jj];
  }
  *(float4*)(out + (size_t)n * DIM + d0) = ov;
}

extern "C" void kernel_launch(void* const* d_in, const int* in_sizes, int n_in,
                              void* d_out, int out_size, void* d_ws, size_t ws_size,
                              hipStream_t stream) {
  const float* x     = (const float*)d_in[0];
  const float* gW    = (const float*)d_in[1];
  const float* gb    = (const float*)d_in[2];
  const float* W1    = (const float*)d_in[3];
  const float* b1    = (const float*)d_in[4];
  const float* W2    = (const float*)d_in[5];
  const float* b2    = (const float*)d_in[6];
  const float* gamma = (const float*)d_in[7];
  const float* beta  = (const float*)d_in[8];
  float* out = (float*)d_out;

  // workspace layout (~166 MB), all chunks 16B-aligned
  char* w = (char*)d_ws;
  unsigned short* W1f = (unsigned short*)w; w += (size_t)NE * HID * DIM * 2;
  unsigned short* W2f = (unsigned short*)w; w += (size_t)NE * DIM * HID * 2;
  unsigned short* He  = (unsigned short*)w; w += (size_t)CAPP * HID * 2;
  unsigned short* AbY = (unsigned short*)w; w += (size_t)CAPP * DIM * 2;  // Ab1, then yb (aliased)
  int*   row_token    = (int*)w;            w += (size_t)CAPP * 4;
  float* row_gate     = (float*)w;          w += (size_t)CAPP * 4;
  int*   tok_e        = (int*)w;            w += (size_t)NPAIR * 4;
  float* tok_g        = (float*)w;          w += (size_t)NPAIR * 4;
  int*   pair_slot    = (int*)w;            w += (size_t)NPAIR * 4;
  int*   cursor       = (int*)w;            w += 64;                 // cursor[8] (zeroed by prep)
  int*   poffs        = (int*)w;            w += 64;                 // poffs[9]
  int*   cnt_out      = (int*)w;            w += 64;                 // cnt[8]
  int*   pcnt         = (int*)w;            w += (size_t)R_BLOCKS * NE * 4;
  float* pimp         = (float*)w;          w += (size_t)R_BLOCKS * NE * 4;
  float* pent         = (float*)w;          w += (size_t)R_BLOCKS * 4;

  unsigned short* Ab1 = AbY;                // gemm1 input (dead after gemm1)
  unsigned short* yb  = AbY;                // gemm2 output (written after Ab1 dead)

  // 6 enqueues: prep (w2f + router), scatter, gather, gemm1, gemm2, ln.
  prep_kernel<<<W2F_BLOCKS + R_BLOCKS, 256, 0, stream>>>(
      W1, W2, W1f, W2f, x, gW, gb, tok_e, tok_g, pcnt, pimp, pent, cursor);
  scatter_kernel<<<N_TOK / 256, 256, 0, stream>>>(
      tok_e, tok_g, pcnt, pimp, pent, cursor, poffs, cnt_out, out + TAIL,
      row_token, row_gate, pair_slot);
  gather_a1<<<GA_BLOCKS, 256, 0, stream>>>(x, row_token, cnt_out, poffs, Ab1);
  expert_gemm1<<<GEMM_BLOCKS, 256, 0, stream>>>(Ab1, W1f, b1, poffs, He);
  expert_gemm2<<<GEMM_BLOCKS, 256, 0, stream>>>(He, W2f, poffs, yb);
  ln_kernel<<<N_TOK, 256, 0, stream>>>(x, yb, tok_e, tok_g, pair_slot, b2, gamma, beta, out);
}

// Round 14
// 440.010 us; speedup vs baseline: 1.1265x; 1.1265x over previous
//
#include <hip/hip_runtime.h>
#include <math.h>

#define N_TOK 8192
#define DIM   1024
#define HID   2048
#define NE    8
#define NPAIR (N_TOK * 2)          // 16384 (token, expert) pairs exactly
#define CAPP  (NPAIR + NE * 128)   // 17408: expert regions padded to 128 rows
#define TAIL  (N_TOK * DIM)        // offset of scalar outputs in d_out

typedef __bf16 bf16x8_t __attribute__((ext_vector_type(8)));
typedef float  f32x4_t  __attribute__((ext_vector_type(4)));

__device__ __forceinline__ unsigned short f2bf(float f) {
  union { float f; unsigned u; } v; v.f = f;
  unsigned r = v.u + 0x7fffu + ((v.u >> 16) & 1u);   // RNE
  return (unsigned short)(r >> 16);
}

__device__ __forceinline__ float bf2f(unsigned short h) {
  union { unsigned u; float f; } v; v.u = ((unsigned)h) << 16;
  return v.f;
}

// erff kept in gemm1 (measured ladder: direct+erff=112us < staged+fast=124
// < direct+fast=152). The libm erff's VALU pacing lets direct u16 stores
// drain under the next tile's K-loop without RMW bursts.
__device__ __forceinline__ float gelu_exact(float v) {
  return 0.5f * v * (1.f + erff(v * 0.70710678118654752440f));
}

// async global->LDS DMA, 16B/lane; LDS base wave-uniform, HW scatters lane*16.
__device__ __forceinline__ void load16_lds(const void* g, void* l) {
  __builtin_amdgcn_global_load_lds(
      (const __attribute__((address_space(1))) unsigned int*)g,
      (__attribute__((address_space(3))) unsigned int*)l, 16, 0, 0);
}

// =======================================================================
// Fragment-chunk global layout (R4): a matrix [R rows][Kd k] is stored as
// 1KB chunks; chunk c = (r>>4)*(Kd/32) + (k>>5); within a chunk, lane
// l = (k>>3&3)*16 + (r&15) owns 16B = 8 shorts (k&7 fastest).
//
// GEMMs: persistent 1024 blocks (4/CU hard cap), R4 inner loop (128x128
// tile, 4 waves, BK=64, 32KB LDS), XCD-bijective swizzle + STRIDE tile
// loop. R17 post-mortem: balanced contiguous ranges REGRESSED both GEMMs
// (gemm1 111->133, FETCH 123->166MB): stride keeps all blocks in one
// contiguous 1024-tile window -> XCD k's instantaneous A-panel set = 8
// panels = 2MB (fits L2); per-block ranges de-phase the blocks -> ~17
// panels = 4.25MB > 4MB L2 -> thrash. R18 reverts to R16's stride loop
// exactly; keeps the 6-launch prep fusion (R17's (b), which passed).
// =======================================================================

#define W2F_BLOCKS 4096
#define R_BLOCKS   512
#define R_TPW      (N_TOK / (R_BLOCKS * 4))   // 4 tokens per wave

// ---------------- weights fp32 [z][Kd][R] -> frag-chunk bf16 (coalesced) ----------------
template<int KD, int RR>
__device__ __forceinline__ void w2f_body(const float* __restrict__ src,
                                         unsigned short* __restrict__ dst,
                                         int bx, int kblk, int z,
                                         unsigned short (*L)[34], int t) {
  constexpr int KD32 = KD / 32;
  int r0 = bx << 8;
  const float* s = src + (size_t)z * KD * RR + (size_t)(kblk * 32) * RR + r0 + t;
  #pragma unroll
  for (int kk = 0; kk < 32; ++kk)
    L[t][kk] = f2bf(s[(size_t)kk * RR]);   // 256 consecutive floats per kk: 1KB coalesced
  __syncthreads();
  int lane = t & 63, m16 = lane & 15, q = lane >> 4;
  unsigned short* d = dst + (size_t)z * KD * RR;
  #pragma unroll
  for (int p = 0; p < 4; ++p) {
    int ci = p * 4 + (t >> 6);            // chunk-in-block 0..15
    int c = ((r0 >> 4) + ci) * KD32 + kblk;
    uint4 v = *(const uint4*)&L[ci * 16 + m16][q * 8];   // 8 shorts k = q*8..q*8+7
    *(uint4*)(d + (size_t)c * 512 + lane * 8) = v;
  }
}

// prep: blocks [0,4096) convert weights; blocks [4096,4608) run the router,
// writing PER-BLOCK partial stats (no cross-block races; no zero-init needed).
// Router block 0 zeroes cursor (consumed only by the later scatter kernel).
__global__ __launch_bounds__(256) void prep_kernel(
    const float* __restrict__ W1, const float* __restrict__ W2,
    unsigned short* __restrict__ W1f, unsigned short* __restrict__ W2f,
    const float* __restrict__ x, const float* __restrict__ gW, const float* __restrict__ gb,
    int* __restrict__ tok_e, float* __restrict__ tok_g,
    int* __restrict__ pcnt,      // [R_BLOCKS][NE]
    float* __restrict__ pimp,    // [R_BLOCKS][NE]
    float* __restrict__ pent,    // [R_BLOCKS]
    int* __restrict__ cursor) {  // [NE]
  __shared__ unsigned short L[256][34];   // w2f path
  __shared__ int s_cnt[NE];               // router path
  __shared__ float s_imp[NE];
  __shared__ float s_ent;
  int t = threadIdx.x;
  int f = blockIdx.x;
  if (f < 2048) {
    int z = f >> 8, r = f & 255;
    w2f_body<DIM, HID>(W1, W1f, r & 7, r >> 3, z, L, t);
    return;
  }
  if (f < W2F_BLOCKS) {
    int f2 = f - 2048;
    int z = f2 >> 8, r = f2 & 255;
    w2f_body<HID, DIM>(W2, W2f, r & 3, r >> 2, z, L, t);
    return;
  }
  // ---------------- router path ----------------
  int rb = f - W2F_BLOCKS;                // 0..511
  if (rb == 0 && t < NE) cursor[t] = 0;   // safe: scatter runs in a later kernel
  if (t < NE) { s_cnt[t] = 0; s_imp[t] = 0.f; }
  if (t == 0) s_ent = 0.f;
  __syncthreads();
  int wid = t >> 6, lane = t & 63;
  int t0 = (rb * 4 + wid) * R_TPW;
  float imp_loc[8] = {0.f, 0.f, 0.f, 0.f, 0.f, 0.f, 0.f, 0.f};
  float ent_loc = 0.f;
  for (int tt = 0; tt < R_TPW; ++tt) {
    int n = t0 + tt;
    const float* xr = x + (size_t)n * DIM;
    float p[8] = {0.f, 0.f, 0.f, 0.f, 0.f, 0.f, 0.f, 0.f};
    #pragma unroll
    for (int it = 0; it < DIM / 64; ++it) {
      int d = lane + (it << 6);
      float xv = xr[d];
      const float4* g4 = (const float4*)(gW + (size_t)d * NE);
      float4 a = g4[0], b = g4[1];
      p[0] += xv * a.x; p[1] += xv * a.y; p[2] += xv * a.z; p[3] += xv * a.w;
      p[4] += xv * b.x; p[5] += xv * b.y; p[6] += xv * b.z; p[7] += xv * b.w;
    }
    #pragma unroll
    for (int e = 0; e < 8; ++e)
      for (int o = 32; o > 0; o >>= 1) p[e] += __shfl_down(p[e], o, 64);
    if (lane == 0) {
      float lg[8];
      #pragma unroll
      for (int e = 0; e < 8; ++e) lg[e] = p[e] + gb[e];
      int i0 = 0;
      #pragma unroll
      for (int e = 1; e < 8; ++e) if (lg[e] > lg[i0]) i0 = e;   // ties -> lowest idx
      int i1 = (i0 == 0) ? 1 : 0;
      #pragma unroll
      for (int e = 0; e < 8; ++e) if (e != i0 && lg[e] > lg[i1]) i1 = e;
      float d1 = expf(lg[i1] - lg[i0]);
      float g0 = 1.f / (1.f + d1);
      float g1 = d1 * g0;
      tok_e[2 * n] = i0; tok_e[2 * n + 1] = i1;
      tok_g[2 * n] = g0; tok_g[2 * n + 1] = g1;
      atomicAdd(&s_cnt[i0], 1);
      atomicAdd(&s_cnt[i1], 1);
      float mx = lg[i0], s = 0.f, pe[8];
      #pragma unroll
      for (int e = 0; e < 8; ++e) { pe[e] = expf(lg[e] - mx); s += pe[e]; }
      float inv = 1.f / s;
      #pragma unroll
      for (int e = 0; e < 8; ++e) {
        float pr = pe[e] * inv;
        imp_loc[e] += pr;
        ent_loc -= pr * logf(pr + 1e-8f);
      }
    }
  }
  if (lane == 0) {
    #pragma unroll
    for (int e = 0; e < 8; ++e) atomicAdd(&s_imp[e], imp_loc[e]);
    atomicAdd(&s_ent, ent_loc);
  }
  __syncthreads();
  if (t < NE) { pcnt[rb * NE + t] = s_cnt[t]; pimp[rb * NE + t] = s_imp[t]; }
  if (t == NE) pent[rb] = s_ent;
}

// ---------------- scatter: reduce partials, bucket pairs, publish stats ----------------
__global__ __launch_bounds__(256) void scatter_kernel(
    const int* __restrict__ tok_e, const float* __restrict__ tok_g,
    const int* __restrict__ pcnt, const float* __restrict__ pimp,
    const float* __restrict__ pent,
    int* __restrict__ cursor, int* __restrict__ poffs_g, int* __restrict__ cnt_out,
    float* __restrict__ out_tail,
    int* __restrict__ row_token, float* __restrict__ row_gate,
    int* __restrict__ pair_slot) {
  __shared__ int s_cnt[NE], s_base[NE], s_rank[NE];
  __shared__ int g_cnt[NE];
  __shared__ float g_imp[NE], g_ent;
  int tid = threadIdx.x;
  if (tid < NE) { s_cnt[tid] = 0; s_rank[tid] = 0; g_cnt[tid] = 0; g_imp[tid] = 0.f; }
  if (tid == 0) g_ent = 0.f;
  __syncthreads();
  // reduce pcnt[512][8]: thread t -> expert e=t&7, row-group rg=t>>3 (32 groups x 16 rows)
  {
    int e = tid & 7, rg = tid >> 3;
    int acc = 0;
    #pragma unroll
    for (int r = 0; r < 16; ++r) acc += pcnt[(rg * 16 + r) * NE + e];
    atomicAdd(&g_cnt[e], acc);
  }
  if (blockIdx.x == 0) {                  // block 0 also reduces imp/ent
    int e = tid & 7, rg = tid >> 3;
    float fa = 0.f;
    #pragma unroll
    for (int r = 0; r < 16; ++r) fa += pimp[(rg * 16 + r) * NE + e];
    atomicAdd(&g_imp[e], fa);
    float ea = pent[tid] + pent[tid + 256];
    atomicAdd(&g_ent, ea);
  }
  int n = blockIdx.x * 256 + tid;
  int e0 = tok_e[2 * n], e1 = tok_e[2 * n + 1];
  atomicAdd(&s_cnt[e0], 1);
  atomicAdd(&s_cnt[e1], 1);
  __syncthreads();
  if (tid < NE) {
    int po = 0;
    for (int e = 0; e < tid; ++e) po += ((g_cnt[e] + 127) >> 7) << 7;   // padded prefix
    s_base[tid] = po + atomicAdd(&cursor[tid], s_cnt[tid]);
  }
  __syncthreads();
  int r0 = atomicAdd(&s_rank[e0], 1);
  int s0 = s_base[e0] + r0;
  row_token[s0] = n; row_gate[s0] = tok_g[2 * n]; pair_slot[2 * n] = s0;
  int r1 = atomicAdd(&s_rank[e1], 1);
  int s1 = s_base[e1] + r1;
  row_token[s1] = n; row_gate[s1] = tok_g[2 * n + 1]; pair_slot[2 * n + 1] = s1;
  if (blockIdx.x == 0 && tid == 0) {
    const float invN = 1.f / (float)N_TOK;
    int off = 0; float bal = 0.f, util = 0.f;
    for (int e = 0; e < NE; ++e) {
      poffs_g[e] = off;
      cnt_out[e] = g_cnt[e];
      off += ((g_cnt[e] + 127) >> 7) << 7;
      float ld = (float)g_cnt[e] * invN;
      float im = g_imp[e] * invN;
      out_tail[3 + e] = ld;        // load
      out_tail[11 + e] = im;       // importance
      bal += im * ld;
      util -= ld * logf(ld + 1e-8f);
    }
    poffs_g[NE] = off;
    out_tail[0] = (float)NE * bal; // balance_loss
    out_tail[1] = g_ent * invN;    // entropy
    out_tail[2] = util;            // utilization_entropy
  }
}

// ---------------- gather bucketed A (x rows -> frag-chunk bf16, Kd=1024) ----------------
#define GA_BLOCKS ((CAPP >> 4) * 32 / 4)   // 8704 worst-case (4 chunks/block)
__global__ __launch_bounds__(256) void gather_a1(
    const float* __restrict__ x, const int* __restrict__ row_token,
    const int* __restrict__ cnt, const int* __restrict__ poffs,
    unsigned short* __restrict__ Ab1) {
  int po[NE + 1];
  #pragma unroll
  for (int i = 0; i <= NE; ++i) po[i] = poffs[i];
  int nch = (po[NE] >> 4) * 32;            // actual total chunks
  int cl = blockIdx.x * 4 + (threadIdx.x >> 6);
  if (cl >= nch) return;                   // wave-uniform exit
  int lane = threadIdx.x & 63, m16 = lane & 15, q = lane >> 4;
  int sb = cl >> 5, kblk = cl & 31;
  int slot = (sb << 4) + m16;
  int e = 0;
  #pragma unroll
  for (int k = 1; k < NE; ++k) e += (po[k] <= slot) ? 1 : 0;   // monotone scan
  int sl = slot - po[e];
  int tok = (sl < cnt[e]) ? row_token[slot] : 0;   // pad rows: token 0 (finite)
  int k = kblk * 32 + q * 8;
  const float4* sp = (const float4*)(x + (size_t)tok * DIM + k);
  float4 v0 = sp[0], v1 = sp[1];
  unsigned short t[8] = {f2bf(v0.x), f2bf(v0.y), f2bf(v0.z), f2bf(v0.w),
                         f2bf(v1.x), f2bf(v1.y), f2bf(v1.z), f2bf(v1.w)};
  *(uint4*)(Ab1 + ((size_t)sb * 32 + kblk) * 512 + lane * 8) = *(uint4*)t;
}

#define GEMM_BLOCKS 1024   // 4 blocks/CU x 256 CU (hard cap: 128 regs/wave, m69)

// XCD-bijective swizzle (T1): 1024 % 8 == 0 so the simple form is bijective.
__device__ __forceinline__ int xcd_swz(int bid) {
  return (bid & 7) * (GEMM_BLOCKS >> 3) + (bid >> 3);
}

// ---------------- GEMM1: He = gelu(Ab1 @ W1f + b1), He in frag order (Kd=2048) ----------------
// R16-exact: persistent, STRIDE tile loop, direct u16 stores + erff.
__global__ __launch_bounds__(256, 4) void expert_gemm1(
    const unsigned short* __restrict__ Ab1,   // frag, Kd32=32
    const unsigned short* __restrict__ W1f,   // [E] frag, rows=HID, Kd32=32
    const float* __restrict__ b1,             // [E][H]
    const int* __restrict__ poffs,
    unsigned short* __restrict__ He) {        // frag, rows=CAPP, Kd32=64
  __shared__ __align__(16) unsigned short As[8192], Bs[8192];
  __shared__ int s_po[NE + 1];
  int tid = threadIdx.x, wid = tid >> 6, lane = tid & 63;
  if (tid <= NE) s_po[tid] = poffs[tid];
  __syncthreads();
  int nt = (s_po[NE] >> 7) << 4;              // row-tiles(128) x 16 col-tiles
  int m16 = lane & 15, q = lane >> 4;
  int wr = (wid & 1) << 6, wc = (wid >> 1) << 6;
  int ra = wr >> 4, rc = wc >> 4;
  unsigned short* lA = As + wid * 4 * 512;
  unsigned short* lB = Bs + wid * 4 * 512;
  f32x4_t zero4 = {0.f, 0.f, 0.f, 0.f};
  int bid0 = xcd_swz(blockIdx.x);

  for (int tile = bid0; tile < nt; tile += GEMM_BLOCKS) {
    int rt = tile >> 4, ct = tile & 15;
    int col0 = ct << 7;
    int row0 = rt << 7;                       // absolute slot row (region-aligned)
    int e = 0;
    while (e + 1 < NE && s_po[e + 1] <= row0) ++e;
    const unsigned short* Ag = Ab1 + ((size_t)((rt << 3) + wid * 2) * 32) * 512 + lane * 8;
    const unsigned short* Bg = W1f + (size_t)e * HID * DIM
                             + ((size_t)((col0 >> 4) + wid * 2) * 32) * 512 + lane * 8;
    f32x4_t acc[4][4];
    #pragma unroll
    for (int i = 0; i < 4; ++i)
      #pragma unroll
      for (int j = 0; j < 4; ++j) acc[i][j] = zero4;

    for (int k0 = 0; k0 < DIM; k0 += 64) {
      int kc = (k0 >> 5) * 512;
      load16_lds(Ag + kc,                  lA);
      load16_lds(Ag + kc + 512,            lA + 512);
      load16_lds(Ag + kc + 32 * 512,       lA + 1024);
      load16_lds(Ag + kc + 32 * 512 + 512, lA + 1536);
      load16_lds(Bg + kc,                  lB);
      load16_lds(Bg + kc + 512,            lB + 512);
      load16_lds(Bg + kc + 32 * 512,       lB + 1024);
      load16_lds(Bg + kc + 32 * 512 + 512, lB + 1536);
      __syncthreads();
      #pragma unroll
      for (int ks = 0; ks < 2; ++ks) {
        bf16x8_t a[4], b[4];
        #pragma unroll
        for (int i = 0; i < 4; ++i) {
          a[i] = *(const bf16x8_t*)&As[((ra + i) * 2 + ks) * 512 + lane * 8];
          b[i] = *(const bf16x8_t*)&Bs[((rc + i) * 2 + ks) * 512 + lane * 8];
        }
        #pragma unroll
        for (int i = 0; i < 4; ++i)
          #pragma unroll
          for (int j = 0; j < 4; ++j)
            acc[i][j] = __builtin_amdgcn_mfma_f32_16x16x32_bf16(a[i], b[j], acc[i][j], 0, 0, 0);
      }
      __syncthreads();
    }

    const float* b1e = b1 + (size_t)e * HID;
    int sb = rt << 3;
    #pragma unroll
    for (int i = 0; i < 4; ++i) {
      size_t sblk = (size_t)(sb + ra + i);
      #pragma unroll
      for (int rr = 0; rr < 4; ++rr) {
        int s15 = q * 4 + rr;   // slot & 15
        #pragma unroll
        for (int j = 0; j < 4; ++j) {
          int col = col0 + wc + j * 16 + m16;
          float v = acc[i][j][rr] + b1e[col];
          size_t off = (sblk * 64 + (col >> 5)) * 512 + (((col >> 3) & 3) * 16 + s15) * 8 + (col & 7);
          He[off] = f2bf(gelu_exact(v));
        }
      }
    }
  }
}

// ---------------- GEMM2: yb[slot] = He @ W2f (row-major out; bias+gate in LN) ----------------
__global__ __launch_bounds__(256, 4) void expert_gemm2(
    const unsigned short* __restrict__ He,    // frag, Kd32=64
    const unsigned short* __restrict__ W2f,   // [E] frag, rows=DIM, Kd32=64
    const int* __restrict__ poffs,
    unsigned short* __restrict__ yb) {        // [CAPP][DIM] row-major
  __shared__ __align__(16) unsigned short As[8192], Bs[8192];
  __shared__ int s_po[NE + 1];
  int tid = threadIdx.x, wid = tid >> 6, lane = tid & 63;
  if (tid <= NE) s_po[tid] = poffs[tid];
  __syncthreads();
  int nt = (s_po[NE] >> 7) << 3;              // row-tiles(128) x 8 col-tiles
  int m16 = lane & 15, q = lane >> 4;
  int wr = (wid & 1) << 6, wc = (wid >> 1) << 6;
  int ra = wr >> 4, rc = wc >> 4;
  unsigned short* lA = As + wid * 4 * 512;
  unsigned short* lB = Bs + wid * 4 * 512;
  f32x4_t zero4 = {0.f, 0.f, 0.f, 0.f};
  int bid0 = xcd_swz(blockIdx.x);

  for (int tile = bid0; tile < nt; tile += GEMM_BLOCKS) {
    int rt = tile >> 3, ct = tile & 7;
    int row0 = rt << 7;
    int col0 = ct << 7;
    int e = 0;
    while (e + 1 < NE && s_po[e + 1] <= row0) ++e;
    const unsigned short* Ag = He + ((size_t)((rt << 3) + wid * 2) * 64) * 512 + lane * 8;
    const unsigned short* Bg = W2f + (size_t)e * DIM * HID
                             + ((size_t)((col0 >> 4) + wid * 2) * 64) * 512 + lane * 8;
    f32x4_t acc[4][4];
    #pragma unroll
    for (int i = 0; i < 4; ++i)
      #pragma unroll
      for (int j = 0; j < 4; ++j) acc[i][j] = zero4;

    for (int k0 = 0; k0 < HID; k0 += 64) {
      int kc = (k0 >> 5) * 512;
      load16_lds(Ag + kc,                  lA);
      load16_lds(Ag + kc + 512,            lA + 512);
      load16_lds(Ag + kc + 64 * 512,       lA + 1024);
      load16_lds(Ag + kc + 64 * 512 + 512, lA + 1536);
      load16_lds(Bg + kc,                  lB);
      load16_lds(Bg + kc + 512,            lB + 512);
      load16_lds(Bg + kc + 64 * 512,       lB + 1024);
      load16_lds(Bg + kc + 64 * 512 + 512, lB + 1536);
      __syncthreads();
      #pragma unroll
      for (int ks = 0; ks < 2; ++ks) {
        bf16x8_t a[4], b[4];
        #pragma unroll
        for (int i = 0; i < 4; ++i) {
          a[i] = *(const bf16x8_t*)&As[((ra + i) * 2 + ks) * 512 + lane * 8];
          b[i] = *(const bf16x8_t*)&Bs[((rc + i) * 2 + ks) * 512 + lane * 8];
        }
        #pragma unroll
        for (int i = 0; i < 4; ++i)
          #pragma unroll
          for (int j = 0; j < 4; ++j)
            acc[i][j] = __builtin_amdgcn_mfma_f32_16x16x32_bf16(a[i], b[j], acc[i][j], 0, 0, 0);
      }
      __syncthreads();
    }

    #pragma unroll
    for (int i = 0; i < 4; ++i) {
      #pragma unroll
      for (int rr = 0; rr < 4; ++rr) {
        size_t slot = (size_t)(row0 + wr + i * 16 + q * 4 + rr);
        #pragma unroll
        for (int j = 0; j < 4; ++j) {
          int col = col0 + wc + j * 16 + m16;
          yb[slot * DIM + col] = f2bf(acc[i][j][rr]);
        }
      }
    }
  }
}

// ---------------- gather + gate + bias + residual + LayerNorm (vectorized) ----------------
__global__ __launch_bounds__(256) void ln_kernel(
    const float* __restrict__ x, const unsigned short* __restrict__ yb,
    const int* __restrict__ tok_e, const float* __restrict__ tok_g,
    const int* __restrict__ pair_slot, const float* __restrict__ b2,
    const float* __restrict__ gamma, const float* __restrict__ beta,
    float* __restrict__ out) {
  int n = blockIdx.x, tid = threadIdx.x;
  int e0 = tok_e[2 * n], e1 = tok_e[2 * n + 1];
  float g0 = tok_g[2 * n], g1 = tok_g[2 * n + 1];
  size_t s0 = (size_t)pair_slot[2 * n], s1 = (size_t)pair_slot[2 * n + 1];
  const float* xr = x + (size_t)n * DIM;
  const unsigned short* y0 = yb + s0 * DIM;
  const unsigned short* y1 = yb + s1 * DIM;
  const float* b2e0 = b2 + (size_t)e0 * DIM;
  const float* b2e1 = b2 + (size_t)e1 * DIM;
  int d0 = tid << 2;   // thread owns elements d0..d0+3 (256*4 = 1024)
  float4 xv  = *(const float4*)(xr + d0);
  ushort4 yv0 = *(const ushort4*)(y0 + d0);
  ushort4 yv1 = *(const ushort4*)(y1 + d0);
  float4 bv0 = *(const float4*)(b2e0 + d0);
  float4 bv1 = *(const float4*)(b2e1 + d0);
  float z[4], s = 0.f, s2 = 0.f;
  {
    const float* xp = (const float*)&xv;
    const unsigned short* y0p = (const unsigned short*)&yv0;
    const unsigned short* y1p = (const unsigned short*)&yv1;
    const float* b0p = (const float*)&bv0;
    const float* b1p = (const float*)&bv1;
    #pragma unroll
    for (int jj = 0; jj < 4; ++jj) {
      float v = xp[jj] + g0 * (bf2f(y0p[jj]) + b0p[jj]) + g1 * (bf2f(y1p[jj]) + b1p[jj]);
      z[jj] = v; s += v; s2 += v * v;
    }
  }
  for (int o = 32; o > 0; o >>= 1) { s += __shfl_down(s, o, 64); s2 += __shfl_down(s2, o, 64); }
  __shared__ float rs[4], rs2[4];
  int wid = tid >> 6, lane = tid & 63;
  if (lane == 0) { rs[wid] = s; rs2[wid] = s2; }
  __syncthreads();
  float ts = rs[0] + rs[1] + rs[2] + rs[3];
  float ts2 = rs2[0] + rs2[1] + rs2[2] + rs2[3];
  float mu = ts * (1.f / DIM);
  float var = ts2 * (1.f / DIM) - mu * mu;
  float rstd = rsqrtf(var + 1e-5f);
  float4 gv = *(const float4*)(gamma + d0);
  float4 bv = *(const float4*)(beta + d0);
  float4 ov;
  {
    const float* gp = (const float*)&gv;
    const float* bp = (const float*)&bv;
    float* op = (float*)&ov;
    #pragma unroll
    for (int jj = 0; jj < 4; ++jj)
      op[jj] = (z[jj] - mu) * rstd * gp[jj] + bp[jj];
  }
  *(float4*)(out + (size_t)n * DIM + d0) = ov;
}

extern "C" void kernel_launch(void* const* d_in, const int* in_sizes, int n_in,
                              void* d_out, int out_size, void* d_ws, size_t ws_size,
                              hipStream_t stream) {
  const float* x     = (const float*)d_in[0];
  const float* gW    = (const float*)d_in[1];
  const float* gb    = (const float*)d_in[2];
  const float* W1    = (const float*)d_in[3];
  const float* b1    = (const float*)d_in[4];
  const float* W2    = (const float*)d_in[5];
  const float* b2    = (const float*)d_in[6];
  const float* gamma = (const float*)d_in[7];
  const float* beta  = (const float*)d_in[8];
  float* out = (float*)d_out;

  // workspace layout (~166 MB), all chunks 16B-aligned
  char* w = (char*)d_ws;
  unsigned short* W1f = (unsigned short*)w; w += (size_t)NE * HID * DIM * 2;
  unsigned short* W2f = (unsigned short*)w; w += (size_t)NE * DIM * HID * 2;
  unsigned short* He  = (unsigned short*)w; w += (size_t)CAPP * HID * 2;
  unsigned short* AbY = (unsigned short*)w; w += (size_t)CAPP * DIM * 2;  // Ab1, then yb (aliased)
  int*   row_token    = (int*)w;            w += (size_t)CAPP * 4;
  float* row_gate     = (float*)w;          w += (size_t)CAPP * 4;
  int*   tok_e        = (int*)w;            w += (size_t)NPAIR * 4;
  float* tok_g        = (float*)w;          w += (size_t)NPAIR * 4;
  int*   pair_slot    = (int*)w;            w += (size_t)NPAIR * 4;
  int*   cursor       = (int*)w;            w += 64;                 // cursor[8] (zeroed by prep)
  int*   poffs        = (int*)w;            w += 64;                 // poffs[9]
  int*   cnt_out      = (int*)w;            w += 64;                 // cnt[8]
  int*   pcnt         = (int*)w;            w += (size_t)R_BLOCKS * NE * 4;
  float* pimp         = (float*)w;          w += (size_t)R_BLOCKS * NE * 4;
  float* pent         = (float*)w;          w += (size_t)R_BLOCKS * 4;

  unsigned short* Ab1 = AbY;                // gemm1 input (dead after gemm1)
  unsigned short* yb  = AbY;                // gemm2 output (written after Ab1 dead)

  // 6 enqueues: prep (w2f + router), scatter, gather, gemm1, gemm2, ln.
  prep_kernel<<<W2F_BLOCKS + R_BLOCKS, 256, 0, stream>>>(
      W1, W2, W1f, W2f, x, gW, gb, tok_e, tok_g, pcnt, pimp, pent, cursor);
  scatter_kernel<<<N_TOK / 256, 256, 0, stream>>>(
      tok_e, tok_g, pcnt, pimp, pent, cursor, poffs, cnt_out, out + TAIL,
      row_token, row_gate, pair_slot);
  gather_a1<<<GA_BLOCKS, 256, 0, stream>>>(x, row_token, cnt_out, poffs, Ab1);
  expert_gemm1<<<GEMM_BLOCKS, 256, 0, stream>>>(Ab1, W1f, b1, poffs, He);
  expert_gemm2<<<GEMM_BLOCKS, 256, 0, stream>>>(He, W2f, poffs, yb);
  ln_kernel<<<N_TOK, 256, 0, stream>>>(x, yb, tok_e, tok_g, pair_slot, b2, gamma, beta, out);
}